// Round 7
// baseline (1471.766 us; speedup 1.0000x reference)
//
#include <hip/hip_runtime.h>
#include <math.h>

#define NPIX (480*640)          // == 1200*256 exactly
#define MDIM 960
#define MPIX (MDIM*MDIM)
#define CNT_STRIDE 32           // one 128B line per bin (atomic contention spread)
#define NBLK 1200

// ws layout (f32/u32 units from base)
#define SCAL_OFF 0              // f32[80]: [0..3] pose-derived, ks at 16/32/48/64
#define BAR_OFF  80             // u32[16]: bar[0] = grid-barrier arrival counter
#define OFFS_OFF 96             // u32[10001]
#define SM_OFF   10112          // f32[70000]: 7 planes * 10000
#define POS_OFF  80112          // f32[4*NPIX]; 80112*4 % 16 == 0
#define FEAT_OFF 1308912        // f32[4*NPIX]; 1308912*4 % 16 == 0
// cnt (u32, stride 32, 10000 bins = 1.28MB) ALIASES the start of pos:
// fully consumed by the P2 scan (which completes before any block enters P3).
#define MEMSET_WORDS (POS_OFF + 10000*CNT_STRIDE)   // one memset: scal,bar,offs,sm,cnt

// output layout (floats)
#define OUT_FPMAP 0
#define OUT_MAP   10000
#define OUT_POSE  (10000 + 9*MPIX)

// Hand-rolled grid barrier: monotonic arrival counter in ws (zeroed each launch by
// the host memset). Release on arrival, acquire on spin — device (AGENT) scope, so
// cross-XCD L2 non-coherence is handled at the memory-side coherence point.
// Residency of all 1200 blocks is guaranteed by __launch_bounds__(256,5): 5 blocks/CU
// x 256 CUs = 1280 slots >= 1200; LDS 1.1KB/block; compiler caps VGPRs to fit.
__device__ __forceinline__ void grid_bar(unsigned* bar, unsigned target) {
    __syncthreads();                     // drains each wave's outstanding memory ops
    if (threadIdx.x == 0) {
        __threadfence();                 // agent-scope release of this block's writes
        __hip_atomic_fetch_add(bar, 1u, __ATOMIC_ACQ_REL, __HIP_MEMORY_SCOPE_AGENT);
        while (__hip_atomic_load(bar, __ATOMIC_ACQUIRE, __HIP_MEMORY_SCOPE_AGENT) < target) {
            __builtin_amdgcn_s_sleep(2);
        }
        __threadfence();                 // agent-scope acquire before block proceeds
    }
    __syncthreads();
}

__global__ __launch_bounds__(256, 5) void fused_kernel(const float* __restrict__ obs,
                                                       const float* pose_obs,
                                                       const float* __restrict__ maps_last,
                                                       const float* poses_last,
                                                       float* __restrict__ out,
                                                       float* __restrict__ ws,
                                                       float fcam) {
    float*    scal = ws + SCAL_OFF;
    unsigned* bar  = (unsigned*)ws + BAR_OFF;
    unsigned* offs = (unsigned*)ws + OFFS_OFF;
    float*    sm   = ws + SM_OFF;
    float4*   pos  = (float4*)(ws + POS_OFF);
    float4*   feat = (float4*)(ws + FEAT_OFF);
    unsigned* cnt  = (unsigned*)ws + POS_OFF;   // aliases pos head
    float* out_fp   = out + OUT_FPMAP;
    float* out_map  = out + OUT_MAP;
    float* out_pose = out + OUT_POSE;

    __shared__ float shbuf[280];    // P1: ks-red[16] / P2: wtot[4] / P4: cols[160]+slab[120]

    int tid = threadIdx.x, bid = blockIdx.x;
    int g = bid*256 + tid;
    int lane = tid & 63, wave = tid >> 6;

    // ---------------- P1: count + ks (1 px/thread, state kept in registers) ----------------
    int p = g;                      // NBLK*256 == NPIX exactly
    int i = p / 640, j = p - i*640;
    float d  = obs[3*NPIX + p];
    float f1 = obs[4*NPIX + p];
    float f2 = obs[5*NPIX + p];
    float f3 = obs[6*NPIX + p];
    float f4 = obs[7*NPIX + p];
    float f5 = obs[8*NPIX + p];
    float X = ((float)j - 319.5f) * d / fcam + 250.0f;
    float Z = ((float)(479 - i) - 239.5f) * d / fcam + 88.0f;
    float xs = ((X/5.0f - 50.0f)/100.0f)*2.0f;
    float ys = ((d/5.0f - 50.0f)/100.0f)*2.0f;
    float zs = ((Z/5.0f - 32.0f)/80.0f)*2.0f;
    float pos0 = (xs*100.0f)/2.0f + 50.0f;
    float pos1 = (ys*100.0f)/2.0f + 50.0f;
    float pos2 = (zs*80.0f)/2.0f + 40.0f;
    int bx = (int)floorf(pos0), by = (int)floorf(pos1), bz = (int)floorf(pos2);
    bool valid = (bx >= 0 && bx <= 99 && by >= 0 && by <= 99 && bz >= 0 && bz <= 79);
    unsigned b = 0, rank = 0;
    if (valid) {
        b = (unsigned)(bx*100 + by);
        rank = atomicAdd(&cnt[b*CNT_STRIDE], 1u);
    }
    // ks channel maxima (obs values nonnegative), block-level reduce
    {
        float m0 = f1, m1 = f2, m2 = f3, m3 = f4;
        #pragma unroll
        for (int off = 32; off > 0; off >>= 1) {
            m0 = fmaxf(m0, __shfl_down(m0, off, 64));
            m1 = fmaxf(m1, __shfl_down(m1, off, 64));
            m2 = fmaxf(m2, __shfl_down(m2, off, 64));
            m3 = fmaxf(m3, __shfl_down(m3, off, 64));
        }
        if (lane == 0) {
            shbuf[wave*4+0] = m0; shbuf[wave*4+1] = m1;
            shbuf[wave*4+2] = m2; shbuf[wave*4+3] = m3;
        }
        __syncthreads();
        if (tid < 4) {
            float m = fmaxf(fmaxf(shbuf[0*4+tid], shbuf[1*4+tid]),
                            fmaxf(shbuf[2*4+tid], shbuf[3*4+tid]));
            atomicMax((int*)&scal[16*(tid+1)], __float_as_int(m));
        }
    }
    grid_bar(bar, 1*NBLK);

    // ---------------- P2: scan + pose (block 0 only; other blocks wait at barrier 2) ----------------
    if (bid == 0) {
        unsigned* wtot = (unsigned*)shbuf;
        unsigned sum = 0;
        for (int q = 0; q < 40; q++) {
            int idx = tid*40 + q;
            if (idx < 10000) sum += cnt[idx*CNT_STRIDE];
        }
        unsigned incl = sum;
        #pragma unroll
        for (int off = 1; off < 64; off <<= 1) {
            unsigned u = (unsigned)__shfl_up((int)incl, off, 64);
            if (lane >= off) incl += u;
        }
        if (lane == 63) wtot[wave] = incl;
        __syncthreads();
        unsigned pre = 0;
        for (int w = 0; w < wave; w++) pre += wtot[w];
        unsigned excl = pre + incl - sum;
        unsigned run = excl;
        for (int q = 0; q < 40; q++) {
            int idx = tid*40 + q;
            if (idx < 10000) { offs[idx] = run; run += cnt[idx*CNT_STRIDE]; }
        }
        if (tid == 255) {
            offs[10000] = excl;   // grand total (threads 250..255 contribute 0)
            const float DEGc = 57.29577951308232f;
            float th = poses_last[2] / DEGc;
            float s = sinf(th), c = cosf(th);
            float ny = poses_last[1] + pose_obs[0]*s + pose_obs[1]*c;
            float nx = poses_last[0] + pose_obs[0]*c - pose_obs[1]*s;
            float nt = poses_last[2] + pose_obs[2]*DEGc;
            nt = fmodf(nt - 180.0f, 360.0f) + 180.0f;
            nt = fmodf(nt + 180.0f, 360.0f) - 180.0f;
            out_pose[0] = nx; out_pose[1] = ny; out_pose[2] = nt;
            out_pose[3] = nx; out_pose[4] = ny; out_pose[5] = nt;
            float sx = -((nx*100.0f)/5.0f - 480.0f)/480.0f;
            float sy = -((ny*100.0f)/5.0f - 480.0f)/480.0f;
            float sth = ((90.0f - nt) * 3.14159265358979323846f) / 180.0f;
            scal[0] = cosf(sth);
            scal[1] = sinf(sth);
            scal[2] = sx;
            scal[3] = sy;
        }
    }
    grid_bar(bar, 2*NBLK);   // block 0 arrives last -> cnt fully consumed before pos writes

    // ---------------- P3: scatter straight from registers ----------------
    if (valid) {
        unsigned k = offs[b] + rank;
        pos[k]  = make_float4(pos0, pos1, pos2, f1);
        feat[k] = make_float4(f2, f3, f4, f5);
    }
    grid_bar(bar, 3*NBLK);

    // ---------------- P4: gather (R4 gather_kernel verbatim, grid-strided over 5000 tiles) ----------------
    {
        float* cols = shbuf;            // 2 cols * 80 z
        float* slab = shbuf + 160;      // 2 cols * 12 z * 5 ch
        for (int t = bid; t < 5000; t += NBLK) {
            int x  = t / 50;            // corner-x 0..99
            int gy = t - x*50;          // y-tile 0..49
            int y0 = gy * 2;            // corners y0, y0+1
            float xf = (float)x;
            for (int q = tid; q < 280; q += 256) shbuf[q] = 0.0f;
            __syncthreads();
            if (x >= 1) {               // corner x==0 killed by the safe mask -> all-zero
                int by_lo = (y0 > 0) ? (y0 - 1) : 0;
                int by_hi = y0 + 2;     // exclusive; <= 100 always
                unsigned s0 = offs[(x-1)*100 + by_lo];
                unsigned e0 = offs[(x-1)*100 + by_hi];
                unsigned s1 = offs[x*100 + by_lo];
                unsigned e1 = offs[x*100 + by_hi];
                unsigned n0 = e0 - s0, n = n0 + (e1 - s1);
                unsigned perm = (tid * 33u) & 255u;   // bijection on [0,256): de-correlates voxels
                for (unsigned base = 0; base < n; base += 256) {
                    unsigned idx = base + perm;
                    if (idx >= n) continue;
                    unsigned k = (idx < n0) ? (s0 + idx) : (s1 + idx - n0);
                    float4 a = pos[k];
                    float wx = 1.0f - fabsf(a.x - xf);
                    float bzf = floorf(a.z);
                    bool need = (bzf >= 12.0f) && (bzf < 25.0f);
                    float4 q2 = need ? feat[k] : make_float4(0.f, 0.f, 0.f, 0.f);
                    int cy0i = (int)floorf(a.y);
                    #pragma unroll
                    for (int tt = 0; tt <= 1; tt++) {
                        int cy = cy0i + tt;
                        if (cy <= 0 || cy >= 100) continue;       // reference safe mask
                        if (cy < y0 || cy > y0 + 1) continue;     // owned by this tile?
                        float wy = 1.0f - fabsf(a.y - (float)cy);
                        float w01 = wx * wy;                       // reference multiply order
                        int cb = (cy - y0) * 80;
                        int sbase = (cy - y0) * 12;
                        #pragma unroll
                        for (int c2 = 0; c2 <= 1; c2++) {
                            float p2 = bzf + (float)c2;
                            if (!(p2 > 0.0f && p2 < 80.0f)) continue;
                            float w = w01 * (1.0f - fabsf(a.z - p2));
                            int zi = (int)p2;
                            atomicAdd(&cols[cb + zi], w);
                            if (zi >= 13 && zi < 25) {
                                int sb = (sbase + (zi - 13)) * 5;
                                atomicAdd(&slab[sb+0], w*a.w);
                                atomicAdd(&slab[sb+1], w*q2.x);
                                atomicAdd(&slab[sb+2], w*q2.y);
                                atomicAdd(&slab[sb+3], w*q2.z);
                                atomicAdd(&slab[sb+4], w*q2.w);
                            }
                        }
                    }
                }
            }
            __syncthreads();
            // per-z round, then column sums (matches reference round-then-sum exactly)
            if (wave < 2) {
                int c = wave;               // column within tile
                int z = lane;               // z in [0,64); [64,80) folded by lanes 0..15
                float r0 = rintf(cols[c*80 + z]);
                float all0 = r0;
                if (lane < 16) all0 += rintf(cols[c*80 + 64 + z]);
                bool inb = (z >= 13 && z < 25);
                float a0 = inb ? r0 : 0.0f;
                float a1 = 0.f, a2 = 0.f, a3 = 0.f, a4 = 0.f, a5 = 0.f;
                if (inb) {
                    int sb = (c*12 + (z - 13)) * 5;
                    a1 = rintf(slab[sb+0]);
                    a2 = rintf(slab[sb+1]);
                    a3 = rintf(slab[sb+2]);
                    a4 = rintf(slab[sb+3]);
                    a5 = rintf(slab[sb+4]);
                }
                #pragma unroll
                for (int off = 32; off > 0; off >>= 1) {
                    all0 += __shfl_down(all0, off, 64);
                    a0 += __shfl_down(a0, off, 64);
                    a1 += __shfl_down(a1, off, 64);
                    a2 += __shfl_down(a2, off, 64);
                    a3 += __shfl_down(a3, off, 64);
                    a4 += __shfl_down(a4, off, 64);
                    a5 += __shfl_down(a5, off, 64);
                }
                if (lane == 0) {
                    int tt = (y0 + c)*100 + x;
                    float fp = fminf(a0, 1.0f);
                    float ex = fminf(all0, 1.0f);
                    sm[0*10000 + tt] = fp;
                    sm[1*10000 + tt] = ex;
                    sm[2*10000 + tt] = fminf(a1/5.0f, 1.0f);
                    sm[3*10000 + tt] = fminf(a2/5.0f, 1.0f);
                    sm[4*10000 + tt] = fminf(a3/5.0f, 1.0f);
                    sm[5*10000 + tt] = fminf(a4/5.0f, 1.0f);
                    sm[6*10000 + tt] = fminf(a5/5.0f, 1.0f);
                    out_fp[tt] = fp;
                }
            }
            __syncthreads();
        }
    }
    grid_bar(bar, 4*NBLK);

    // ---------------- P5: final (R4 final_kernel; 4 px/thread, float4 fast path) ----------------
    if (g < 230400) {
        int pp = g*4;
        int y = pp / MDIM, xp = pp - y*MDIM;
        float ct = scal[0], sn = scal[1], sx = scal[2], sy = scal[3];
        const float step = 2.0f/959.0f;
        float gyv = (float)y*step - 1.0f;
        float v = gyv + sy;
        float yim = ((v + 1.0f)*0.5f)*959.0f;
        float gyc = yim*step - 1.0f;
        float xims[4];
        bool act[4];
        bool any = false;
        #pragma unroll
        for (int q = 0; q < 4; q++) {
            float gxv = (float)(xp+q)*step - 1.0f;
            float u = gxv + sx;
            float xim = ((u + 1.0f)*0.5f)*959.0f;
            xims[q] = xim;
            // Early reject: rotation is an isometry; the 4 translation taps lie
            // within sqrt(2) px of the rotated center; >1.5 px outside the active
            // window (rows (479,580), cols (429,530)) -> every sample exactly 0.
            float gxc = xim*step - 1.0f;
            float uc = ct*gxc - sn*gyc;
            float vc = sn*gxc + ct*gyc;
            float xc2 = ((uc + 1.0f)*0.5f)*959.0f;
            float yc2 = ((vc + 1.0f)*0.5f)*959.0f;
            bool a = (xc2 > 427.5f) && (xc2 < 531.5f) && (yc2 > 477.5f) && (yc2 < 581.5f);
            act[q] = a;
            any = any || a;
        }
        if (!any) {
            #pragma unroll
            for (int c = 0; c < 9; c++) {
                float4 ml = *(const float4*)(maps_last + c*MPIX + pp);
                float4 o;
                o.x = fmaxf(ml.x, 0.0f); o.y = fmaxf(ml.y, 0.0f);
                o.z = fmaxf(ml.z, 0.0f); o.w = fmaxf(ml.w, 0.0f);
                *(float4*)(out_map + c*MPIX + pp) = o;
            }
        } else {
            float ks0 = scal[16], ks1 = scal[32], ks2 = scal[48], ks3 = scal[64];
            #pragma unroll
            for (int q = 0; q < 4; q++) {
                int o = pp + q;
                float ts[7] = {0,0,0,0,0,0,0};
                if (act[q]) {
                    float xim = xims[q];
                    float x0f = floorf(xim), y0f = floorf(yim);
                    #pragma unroll
                    for (int ty = 0; ty <= 1; ty++) {
                        float yy = y0f + (float)ty;
                        if (yy < 0.0f || yy > 959.0f) continue;
                        float wyv = 1.0f - fabsf(yim - yy);
                        #pragma unroll
                        for (int tx = 0; tx <= 1; tx++) {
                            float xx = x0f + (float)tx;
                            if (xx < 0.0f || xx > 959.0f) continue;
                            float w = (1.0f - fabsf(xim - xx)) * wyv;
                            float gx1 = xx*step - 1.0f;
                            float gy1 = yy*step - 1.0f;
                            float uu = ct*gx1 - sn*gy1;
                            float vv = sn*gx1 + ct*gy1;
                            float xim2 = ((uu + 1.0f)*0.5f)*959.0f;
                            float yim2 = ((vv + 1.0f)*0.5f)*959.0f;
                            float x02 = floorf(xim2), y02 = floorf(yim2);
                            float rot[7] = {0,0,0,0,0,0,0};
                            #pragma unroll
                            for (int ty2 = 0; ty2 <= 1; ty2++) {
                                float yy2 = y02 + (float)ty2;
                                if (yy2 < 480.0f || yy2 >= 580.0f) continue;  // rows [480,580)
                                float wy2 = 1.0f - fabsf(yim2 - yy2);
                                int yi = (int)yy2 - 480;
                                #pragma unroll
                                for (int tx2 = 0; tx2 <= 1; tx2++) {
                                    float xx2 = x02 + (float)tx2;
                                    if (xx2 < 430.0f || xx2 >= 530.0f) continue;  // cols [430,530)
                                    float w2 = (1.0f - fabsf(xim2 - xx2)) * wy2;
                                    int oo = yi*100 + ((int)xx2 - 430);
                                    #pragma unroll
                                    for (int kk = 0; kk < 7; kk++) rot[kk] += sm[kk*10000 + oo] * w2;
                                }
                            }
                            #pragma unroll
                            for (int kk = 0; kk < 7; kk++) ts[kk] += rot[kk]*w;
                        }
                    }
                }
                float ml;
                ml = maps_last[0*MPIX + o]; out_map[0*MPIX + o] = fmaxf(ml, ts[0]);
                ml = maps_last[1*MPIX + o]; out_map[1*MPIX + o] = fmaxf(ml, ts[1]);
                ml = maps_last[2*MPIX + o]; out_map[2*MPIX + o] = fmaxf(ml, 0.0f);
                ml = maps_last[3*MPIX + o]; out_map[3*MPIX + o] = fmaxf(ml, 0.0f);
                float t4 = ts[2]; t4 = (t4 > 0.0f) ? ks0 : t4;
                ml = maps_last[4*MPIX + o]; out_map[4*MPIX + o] = fmaxf(ml, t4);
                float t5 = ts[3]; t5 = (t5 > 0.0f) ? ks1 : t5;
                ml = maps_last[5*MPIX + o]; out_map[5*MPIX + o] = fmaxf(ml, t5);
                float t6 = ts[4]; t6 = (t6 > 0.0f) ? ks2 : t6;
                ml = maps_last[6*MPIX + o]; out_map[6*MPIX + o] = fmaxf(ml, t6);
                float t7 = ts[5]; t7 = (t7 > 0.0f) ? ks3 : t7;
                ml = maps_last[7*MPIX + o]; out_map[7*MPIX + o] = fmaxf(ml, t7);
                ml = maps_last[8*MPIX + o]; out_map[8*MPIX + o] = fmaxf(ml, ts[6]);
            }
        }
    }
}

extern "C" void kernel_launch(void* const* d_in, const int* in_sizes, int n_in,
                              void* d_out, int out_size, void* d_ws, size_t ws_size,
                              hipStream_t stream) {
    const float* obs        = (const float*)d_in[0];
    const float* pose_obs   = (const float*)d_in[1];
    const float* maps_last  = (const float*)d_in[2];
    const float* poses_last = (const float*)d_in[3];
    float* out  = (float*)d_out;
    float* ws_f = (float*)d_ws;

    // one memset: scal + barrier + offs + sm + cnt (cnt aliases pos head)
    hipMemsetAsync(d_ws, 0, (size_t)MEMSET_WORDS * 4u, stream);

    float fcam = (float)(320.0 / tan(39.5 * M_PI / 180.0));

    fused_kernel<<<NBLK, 256, 0, stream>>>(obs, pose_obs, maps_last, poses_last,
                                           out, ws_f, fcam);
}

// Round 8
// 558.728 us; speedup vs baseline: 2.6341x; 2.6341x over previous
//
#include <hip/hip_runtime.h>
#include <math.h>

#define NPIX (480*640)          // == 1200*256 exactly
#define MDIM 960
#define MPIX (MDIM*MDIM)
#define CNT_STRIDE 32           // one 128B line per bin (atomic contention spread)
#define NBLK 1200

// ws layout (f32/u32 units from base)
#define SCAL_OFF 0              // f32[80]: [0..3] pose-derived, ks at 16/32/48/64
#define BAR_OFF  80             // u32[16]: bar[0] = grid-barrier arrival counter
#define OFFS_OFF 96             // u32[10001]
#define SM_OFF   10112          // f32[70000]: 7 planes * 10000
#define POS_OFF  80112          // f32[4*NPIX]; 80112*4 % 16 == 0
#define FEAT_OFF 1308912        // f32[4*NPIX]; 1308912*4 % 16 == 0
// cnt (u32, stride 32, 10000 bins = 1.28MB) ALIASES the start of pos:
// fully consumed by the P2 scan (which completes before any block enters P3).
#define MEMSET_WORDS (POS_OFF + 10000*CNT_STRIDE)   // one memset: scal,bar,offs,sm,cnt

// output layout (floats)
#define OUT_FPMAP 0
#define OUT_MAP   10000
#define OUT_POSE  (10000 + 9*MPIX)

// Grid barrier, cooperative-groups style. Arrival: RELEASE fetch_add (one L2
// writeback — required: per-XCD L2s are non-coherent, normal stores must reach the
// coherence point). Spin: RELAXED agent-scope atomic load — reads through to the
// coherence point (same path that makes cross-XCD atomicAdd correct) WITHOUT the
// per-poll cache invalidate an ACQUIRE load emits (R7's 6x regression: ~1200
// spinners invalidating L2 every ~130cy put the whole kernel at HBM latency).
// Exit: one ACQUIRE fence. Residency of all 1200 blocks guaranteed by
// __launch_bounds__(256,5): 5 blocks/CU x 256 CUs = 1280 >= 1200 (proven in R7).
__device__ __forceinline__ void grid_bar(unsigned* bar, unsigned target) {
    __syncthreads();
    if (threadIdx.x == 0) {
        __hip_atomic_fetch_add(bar, 1u, __ATOMIC_RELEASE, __HIP_MEMORY_SCOPE_AGENT);
        while (__hip_atomic_load(bar, __ATOMIC_RELAXED, __HIP_MEMORY_SCOPE_AGENT) < target) {
            __builtin_amdgcn_s_sleep(8);
        }
        __builtin_amdgcn_fence(__ATOMIC_ACQUIRE, "agent");
    }
    __syncthreads();
}

__global__ __launch_bounds__(256, 5) void fused_kernel(const float* __restrict__ obs,
                                                       const float* pose_obs,
                                                       const float* __restrict__ maps_last,
                                                       const float* poses_last,
                                                       float* __restrict__ out,
                                                       float* __restrict__ ws,
                                                       float fcam) {
    float*    scal = ws + SCAL_OFF;
    unsigned* bar  = (unsigned*)ws + BAR_OFF;
    unsigned* offs = (unsigned*)ws + OFFS_OFF;
    float*    sm   = ws + SM_OFF;
    float4*   pos  = (float4*)(ws + POS_OFF);
    float4*   feat = (float4*)(ws + FEAT_OFF);
    unsigned* cnt  = (unsigned*)ws + POS_OFF;   // aliases pos head
    float* out_fp   = out + OUT_FPMAP;
    float* out_map  = out + OUT_MAP;
    float* out_pose = out + OUT_POSE;

    __shared__ float shbuf[280];    // P1: ks-red[16] / P2: wtot[4] / P4: cols[160]+slab[120]

    int tid = threadIdx.x, bid = blockIdx.x;
    int g = bid*256 + tid;
    int lane = tid & 63, wave = tid >> 6;

    // ---------------- P1: count + ks (1 px/thread, state kept in registers) ----------------
    int p = g;                      // NBLK*256 == NPIX exactly
    int i = p / 640, j = p - i*640;
    float d  = obs[3*NPIX + p];
    float f1 = obs[4*NPIX + p];
    float f2 = obs[5*NPIX + p];
    float f3 = obs[6*NPIX + p];
    float f4 = obs[7*NPIX + p];
    float f5 = obs[8*NPIX + p];
    float X = ((float)j - 319.5f) * d / fcam + 250.0f;
    float Z = ((float)(479 - i) - 239.5f) * d / fcam + 88.0f;
    float xs = ((X/5.0f - 50.0f)/100.0f)*2.0f;
    float ys = ((d/5.0f - 50.0f)/100.0f)*2.0f;
    float zs = ((Z/5.0f - 32.0f)/80.0f)*2.0f;
    float pos0 = (xs*100.0f)/2.0f + 50.0f;
    float pos1 = (ys*100.0f)/2.0f + 50.0f;
    float pos2 = (zs*80.0f)/2.0f + 40.0f;
    int bx = (int)floorf(pos0), by = (int)floorf(pos1), bz = (int)floorf(pos2);
    bool valid = (bx >= 0 && bx <= 99 && by >= 0 && by <= 99 && bz >= 0 && bz <= 79);
    unsigned b = 0, rank = 0;
    if (valid) {
        b = (unsigned)(bx*100 + by);
        rank = atomicAdd(&cnt[b*CNT_STRIDE], 1u);
    }
    // ks channel maxima (obs values nonnegative), block-level reduce
    {
        float m0 = f1, m1 = f2, m2 = f3, m3 = f4;
        #pragma unroll
        for (int off = 32; off > 0; off >>= 1) {
            m0 = fmaxf(m0, __shfl_down(m0, off, 64));
            m1 = fmaxf(m1, __shfl_down(m1, off, 64));
            m2 = fmaxf(m2, __shfl_down(m2, off, 64));
            m3 = fmaxf(m3, __shfl_down(m3, off, 64));
        }
        if (lane == 0) {
            shbuf[wave*4+0] = m0; shbuf[wave*4+1] = m1;
            shbuf[wave*4+2] = m2; shbuf[wave*4+3] = m3;
        }
        __syncthreads();
        if (tid < 4) {
            float m = fmaxf(fmaxf(shbuf[0*4+tid], shbuf[1*4+tid]),
                            fmaxf(shbuf[2*4+tid], shbuf[3*4+tid]));
            atomicMax((int*)&scal[16*(tid+1)], __float_as_int(m));
        }
    }
    grid_bar(bar, 1*NBLK);

    // ---------------- P2: scan + pose (block 0 only; other blocks wait at barrier 2) ----------------
    if (bid == 0) {
        unsigned* wtot = (unsigned*)shbuf;
        unsigned sum = 0;
        for (int q = 0; q < 40; q++) {
            int idx = tid*40 + q;
            if (idx < 10000) sum += cnt[idx*CNT_STRIDE];
        }
        unsigned incl = sum;
        #pragma unroll
        for (int off = 1; off < 64; off <<= 1) {
            unsigned u = (unsigned)__shfl_up((int)incl, off, 64);
            if (lane >= off) incl += u;
        }
        if (lane == 63) wtot[wave] = incl;
        __syncthreads();
        unsigned pre = 0;
        for (int w = 0; w < wave; w++) pre += wtot[w];
        unsigned excl = pre + incl - sum;
        unsigned run = excl;
        for (int q = 0; q < 40; q++) {
            int idx = tid*40 + q;
            if (idx < 10000) { offs[idx] = run; run += cnt[idx*CNT_STRIDE]; }
        }
        if (tid == 255) {
            offs[10000] = excl;   // grand total (threads 250..255 contribute 0)
            const float DEGc = 57.29577951308232f;
            float th = poses_last[2] / DEGc;
            float s = sinf(th), c = cosf(th);
            float ny = poses_last[1] + pose_obs[0]*s + pose_obs[1]*c;
            float nx = poses_last[0] + pose_obs[0]*c - pose_obs[1]*s;
            float nt = poses_last[2] + pose_obs[2]*DEGc;
            nt = fmodf(nt - 180.0f, 360.0f) + 180.0f;
            nt = fmodf(nt + 180.0f, 360.0f) - 180.0f;
            out_pose[0] = nx; out_pose[1] = ny; out_pose[2] = nt;
            out_pose[3] = nx; out_pose[4] = ny; out_pose[5] = nt;
            float sx = -((nx*100.0f)/5.0f - 480.0f)/480.0f;
            float sy = -((ny*100.0f)/5.0f - 480.0f)/480.0f;
            float sth = ((90.0f - nt) * 3.14159265358979323846f) / 180.0f;
            scal[0] = cosf(sth);
            scal[1] = sinf(sth);
            scal[2] = sx;
            scal[3] = sy;
        }
    }
    grid_bar(bar, 2*NBLK);   // cnt fully consumed before pos writes begin

    // ---------------- P3: scatter straight from registers ----------------
    if (valid) {
        unsigned k = offs[b] + rank;
        pos[k]  = make_float4(pos0, pos1, pos2, f1);
        feat[k] = make_float4(f2, f3, f4, f5);
    }
    grid_bar(bar, 3*NBLK);

    // ---------------- P4: gather (R4 gather_kernel verbatim, grid-strided over 5000 tiles) ----------------
    {
        float* cols = shbuf;            // 2 cols * 80 z
        float* slab = shbuf + 160;      // 2 cols * 12 z * 5 ch
        for (int t = bid; t < 5000; t += NBLK) {
            int x  = t / 50;            // corner-x 0..99
            int gy = t - x*50;          // y-tile 0..49
            int y0 = gy * 2;            // corners y0, y0+1
            float xf = (float)x;
            for (int q = tid; q < 280; q += 256) shbuf[q] = 0.0f;
            __syncthreads();
            if (x >= 1) {               // corner x==0 killed by the safe mask -> all-zero
                int by_lo = (y0 > 0) ? (y0 - 1) : 0;
                int by_hi = y0 + 2;     // exclusive; <= 100 always
                unsigned s0 = offs[(x-1)*100 + by_lo];
                unsigned e0 = offs[(x-1)*100 + by_hi];
                unsigned s1 = offs[x*100 + by_lo];
                unsigned e1 = offs[x*100 + by_hi];
                unsigned n0 = e0 - s0, n = n0 + (e1 - s1);
                unsigned perm = (tid * 33u) & 255u;   // bijection on [0,256): de-correlates voxels
                for (unsigned base = 0; base < n; base += 256) {
                    unsigned idx = base + perm;
                    if (idx >= n) continue;
                    unsigned k = (idx < n0) ? (s0 + idx) : (s1 + idx - n0);
                    float4 a = pos[k];
                    float wx = 1.0f - fabsf(a.x - xf);
                    float bzf = floorf(a.z);
                    bool need = (bzf >= 12.0f) && (bzf < 25.0f);
                    float4 q2 = need ? feat[k] : make_float4(0.f, 0.f, 0.f, 0.f);
                    int cy0i = (int)floorf(a.y);
                    #pragma unroll
                    for (int tt = 0; tt <= 1; tt++) {
                        int cy = cy0i + tt;
                        if (cy <= 0 || cy >= 100) continue;       // reference safe mask
                        if (cy < y0 || cy > y0 + 1) continue;     // owned by this tile?
                        float wy = 1.0f - fabsf(a.y - (float)cy);
                        float w01 = wx * wy;                       // reference multiply order
                        int cb = (cy - y0) * 80;
                        int sbase = (cy - y0) * 12;
                        #pragma unroll
                        for (int c2 = 0; c2 <= 1; c2++) {
                            float p2 = bzf + (float)c2;
                            if (!(p2 > 0.0f && p2 < 80.0f)) continue;
                            float w = w01 * (1.0f - fabsf(a.z - p2));
                            int zi = (int)p2;
                            atomicAdd(&cols[cb + zi], w);
                            if (zi >= 13 && zi < 25) {
                                int sb = (sbase + (zi - 13)) * 5;
                                atomicAdd(&slab[sb+0], w*a.w);
                                atomicAdd(&slab[sb+1], w*q2.x);
                                atomicAdd(&slab[sb+2], w*q2.y);
                                atomicAdd(&slab[sb+3], w*q2.z);
                                atomicAdd(&slab[sb+4], w*q2.w);
                            }
                        }
                    }
                }
            }
            __syncthreads();
            // per-z round, then column sums (matches reference round-then-sum exactly)
            if (wave < 2) {
                int c = wave;               // column within tile
                int z = lane;               // z in [0,64); [64,80) folded by lanes 0..15
                float r0 = rintf(cols[c*80 + z]);
                float all0 = r0;
                if (lane < 16) all0 += rintf(cols[c*80 + 64 + z]);
                bool inb = (z >= 13 && z < 25);
                float a0 = inb ? r0 : 0.0f;
                float a1 = 0.f, a2 = 0.f, a3 = 0.f, a4 = 0.f, a5 = 0.f;
                if (inb) {
                    int sb = (c*12 + (z - 13)) * 5;
                    a1 = rintf(slab[sb+0]);
                    a2 = rintf(slab[sb+1]);
                    a3 = rintf(slab[sb+2]);
                    a4 = rintf(slab[sb+3]);
                    a5 = rintf(slab[sb+4]);
                }
                #pragma unroll
                for (int off = 32; off > 0; off >>= 1) {
                    all0 += __shfl_down(all0, off, 64);
                    a0 += __shfl_down(a0, off, 64);
                    a1 += __shfl_down(a1, off, 64);
                    a2 += __shfl_down(a2, off, 64);
                    a3 += __shfl_down(a3, off, 64);
                    a4 += __shfl_down(a4, off, 64);
                    a5 += __shfl_down(a5, off, 64);
                }
                if (lane == 0) {
                    int tt = (y0 + c)*100 + x;
                    float fp = fminf(a0, 1.0f);
                    float ex = fminf(all0, 1.0f);
                    sm[0*10000 + tt] = fp;
                    sm[1*10000 + tt] = ex;
                    sm[2*10000 + tt] = fminf(a1/5.0f, 1.0f);
                    sm[3*10000 + tt] = fminf(a2/5.0f, 1.0f);
                    sm[4*10000 + tt] = fminf(a3/5.0f, 1.0f);
                    sm[5*10000 + tt] = fminf(a4/5.0f, 1.0f);
                    sm[6*10000 + tt] = fminf(a5/5.0f, 1.0f);
                    out_fp[tt] = fp;
                }
            }
            __syncthreads();
        }
    }
    grid_bar(bar, 4*NBLK);

    // ---------------- P5: final (R4 final_kernel; 4 px/thread, float4 fast path) ----------------
    if (g < 230400) {
        int pp = g*4;
        int y = pp / MDIM, xp = pp - y*MDIM;
        float ct = scal[0], sn = scal[1], sx = scal[2], sy = scal[3];
        const float step = 2.0f/959.0f;
        float gyv = (float)y*step - 1.0f;
        float v = gyv + sy;
        float yim = ((v + 1.0f)*0.5f)*959.0f;
        float gyc = yim*step - 1.0f;
        float xims[4];
        bool act[4];
        bool any = false;
        #pragma unroll
        for (int q = 0; q < 4; q++) {
            float gxv = (float)(xp+q)*step - 1.0f;
            float u = gxv + sx;
            float xim = ((u + 1.0f)*0.5f)*959.0f;
            xims[q] = xim;
            // Early reject: rotation is an isometry; the 4 translation taps lie
            // within sqrt(2) px of the rotated center; >1.5 px outside the active
            // window (rows (479,580), cols (429,530)) -> every sample exactly 0.
            float gxc = xim*step - 1.0f;
            float uc = ct*gxc - sn*gyc;
            float vc = sn*gxc + ct*gyc;
            float xc2 = ((uc + 1.0f)*0.5f)*959.0f;
            float yc2 = ((vc + 1.0f)*0.5f)*959.0f;
            bool a = (xc2 > 427.5f) && (xc2 < 531.5f) && (yc2 > 477.5f) && (yc2 < 581.5f);
            act[q] = a;
            any = any || a;
        }
        if (!any) {
            #pragma unroll
            for (int c = 0; c < 9; c++) {
                float4 ml = *(const float4*)(maps_last + c*MPIX + pp);
                float4 o;
                o.x = fmaxf(ml.x, 0.0f); o.y = fmaxf(ml.y, 0.0f);
                o.z = fmaxf(ml.z, 0.0f); o.w = fmaxf(ml.w, 0.0f);
                *(float4*)(out_map + c*MPIX + pp) = o;
            }
        } else {
            float ks0 = scal[16], ks1 = scal[32], ks2 = scal[48], ks3 = scal[64];
            #pragma unroll
            for (int q = 0; q < 4; q++) {
                int o = pp + q;
                float ts[7] = {0,0,0,0,0,0,0};
                if (act[q]) {
                    float xim = xims[q];
                    float x0f = floorf(xim), y0f = floorf(yim);
                    #pragma unroll
                    for (int ty = 0; ty <= 1; ty++) {
                        float yy = y0f + (float)ty;
                        if (yy < 0.0f || yy > 959.0f) continue;
                        float wyv = 1.0f - fabsf(yim - yy);
                        #pragma unroll
                        for (int tx = 0; tx <= 1; tx++) {
                            float xx = x0f + (float)tx;
                            if (xx < 0.0f || xx > 959.0f) continue;
                            float w = (1.0f - fabsf(xim - xx)) * wyv;
                            float gx1 = xx*step - 1.0f;
                            float gy1 = yy*step - 1.0f;
                            float uu = ct*gx1 - sn*gy1;
                            float vv = sn*gx1 + ct*gy1;
                            float xim2 = ((uu + 1.0f)*0.5f)*959.0f;
                            float yim2 = ((vv + 1.0f)*0.5f)*959.0f;
                            float x02 = floorf(xim2), y02 = floorf(yim2);
                            float rot[7] = {0,0,0,0,0,0,0};
                            #pragma unroll
                            for (int ty2 = 0; ty2 <= 1; ty2++) {
                                float yy2 = y02 + (float)ty2;
                                if (yy2 < 480.0f || yy2 >= 580.0f) continue;  // rows [480,580)
                                float wy2 = 1.0f - fabsf(yim2 - yy2);
                                int yi = (int)yy2 - 480;
                                #pragma unroll
                                for (int tx2 = 0; tx2 <= 1; tx2++) {
                                    float xx2 = x02 + (float)tx2;
                                    if (xx2 < 430.0f || xx2 >= 530.0f) continue;  // cols [430,530)
                                    float w2 = (1.0f - fabsf(xim2 - xx2)) * wy2;
                                    int oo = yi*100 + ((int)xx2 - 430);
                                    #pragma unroll
                                    for (int kk = 0; kk < 7; kk++) rot[kk] += sm[kk*10000 + oo] * w2;
                                }
                            }
                            #pragma unroll
                            for (int kk = 0; kk < 7; kk++) ts[kk] += rot[kk]*w;
                        }
                    }
                }
                float ml;
                ml = maps_last[0*MPIX + o]; out_map[0*MPIX + o] = fmaxf(ml, ts[0]);
                ml = maps_last[1*MPIX + o]; out_map[1*MPIX + o] = fmaxf(ml, ts[1]);
                ml = maps_last[2*MPIX + o]; out_map[2*MPIX + o] = fmaxf(ml, 0.0f);
                ml = maps_last[3*MPIX + o]; out_map[3*MPIX + o] = fmaxf(ml, 0.0f);
                float t4 = ts[2]; t4 = (t4 > 0.0f) ? ks0 : t4;
                ml = maps_last[4*MPIX + o]; out_map[4*MPIX + o] = fmaxf(ml, t4);
                float t5 = ts[3]; t5 = (t5 > 0.0f) ? ks1 : t5;
                ml = maps_last[5*MPIX + o]; out_map[5*MPIX + o] = fmaxf(ml, t5);
                float t6 = ts[4]; t6 = (t6 > 0.0f) ? ks2 : t6;
                ml = maps_last[6*MPIX + o]; out_map[6*MPIX + o] = fmaxf(ml, t6);
                float t7 = ts[5]; t7 = (t7 > 0.0f) ? ks3 : t7;
                ml = maps_last[7*MPIX + o]; out_map[7*MPIX + o] = fmaxf(ml, t7);
                ml = maps_last[8*MPIX + o]; out_map[8*MPIX + o] = fmaxf(ml, ts[6]);
            }
        }
    }
}

extern "C" void kernel_launch(void* const* d_in, const int* in_sizes, int n_in,
                              void* d_out, int out_size, void* d_ws, size_t ws_size,
                              hipStream_t stream) {
    const float* obs        = (const float*)d_in[0];
    const float* pose_obs   = (const float*)d_in[1];
    const float* maps_last  = (const float*)d_in[2];
    const float* poses_last = (const float*)d_in[3];
    float* out  = (float*)d_out;
    float* ws_f = (float*)d_ws;

    // one memset: scal + barrier + offs + sm + cnt (cnt aliases pos head)
    hipMemsetAsync(d_ws, 0, (size_t)MEMSET_WORDS * 4u, stream);

    float fcam = (float)(320.0 / tan(39.5 * M_PI / 180.0));

    fused_kernel<<<NBLK, 256, 0, stream>>>(obs, pose_obs, maps_last, poses_last,
                                           out, ws_f, fcam);
}

// Round 9
// 248.790 us; speedup vs baseline: 5.9157x; 2.2458x over previous
//
#include <hip/hip_runtime.h>
#include <math.h>

#define NPIX (480*640)
#define MDIM 960
#define MPIX (MDIM*MDIM)
#define PACK_M 307201u
#define CNT_STRIDE 32   // one 128B line per bin (atomic contention spread)

// ws layout (u32/f32 units from base)
#define SCAL_OFF 0        // f32[80]: [0..3] pose-derived, ks at 16/32/48/64 (separate lines)
#define OFFS_OFF 80       // u32[10001]
#define SM_OFF   10084    // f32[70000]: 7 planes * 10000
#define PACK_OFF 80084    // u32[NPIX]
#define POS_OFF  387284   // f32[4*NPIX]; byte offset % 16 == 0
#define FEAT_OFF 1616084  // f32[4*NPIX]; byte offset % 16 == 0
// cnt (u32, stride 32, 10000 bins = 1.28MB) ALIASES the start of pos:
// it is fully consumed by scan_pose before scatter writes pos.

// output layout (floats)
#define OUT_FPMAP 0
#define OUT_MAP   10000
#define OUT_POSE  (10000 + 9*MPIX)

// ---------------- count (1 px/thread, bins spread 1 line apart) ----------------
__global__ __launch_bounds__(256) void count_kernel(const float* __restrict__ obs,
                                                    unsigned* __restrict__ cnt,
                                                    unsigned* __restrict__ pack,
                                                    float fcam) {
    int p = blockIdx.x*256 + threadIdx.x;          // 0..307199
    int i = p / 640, j = p - i*640;
    float d = obs[3*NPIX + p];
    float X = ((float)j - 319.5f) * d / fcam + 250.0f;
    float Z = ((float)(479 - i) - 239.5f) * d / fcam + 88.0f;
    float xs = ((X/5.0f - 50.0f)/100.0f)*2.0f;
    float ys = ((d/5.0f - 50.0f)/100.0f)*2.0f;
    float zs = ((Z/5.0f - 32.0f)/80.0f)*2.0f;
    float pos0 = (xs*100.0f)/2.0f + 50.0f;
    float pos1 = (ys*100.0f)/2.0f + 50.0f;
    float pos2 = (zs*80.0f)/2.0f + 40.0f;
    int bx = (int)floorf(pos0), by = (int)floorf(pos1), bz = (int)floorf(pos2);
    unsigned pk = 0xFFFFFFFFu;
    if (bx >= 0 && bx <= 99 && by >= 0 && by <= 99 && bz >= 0 && bz <= 79) {
        unsigned b = (unsigned)(bx*100 + by);
        unsigned rank = atomicAdd(&cnt[b*CNT_STRIDE], 1u);
        pk = b * PACK_M + rank;
    }
    pack[p] = pk;
}

// ---------------- scan (256 threads, one WG) + pose fused; zeroes ks slots ----------------
__global__ __launch_bounds__(256) void scan_pose_kernel(const unsigned* __restrict__ cnt,
                                                        unsigned* __restrict__ offs,
                                                        const float* pose_obs,
                                                        const float* poses_last,
                                                        float* scal, float* out_pose) {
    int tid = threadIdx.x;
    int lane = tid & 63, wave = tid >> 6;
    // zero the ks atomicMax targets (scatter, which runs next, maxes into them)
    if (tid < 4) scal[16*(tid+1)] = 0.0f;
    unsigned lc[40];
    unsigned sum = 0;
    #pragma unroll
    for (int q = 0; q < 40; q++) {
        int idx = tid*40 + q;
        lc[q] = (idx < 10000) ? cnt[idx*CNT_STRIDE] : 0u;
        sum += lc[q];
    }
    unsigned incl = sum;
    #pragma unroll
    for (int off = 1; off < 64; off <<= 1) {
        unsigned u = (unsigned)__shfl_up((int)incl, off, 64);
        if (lane >= off) incl += u;
    }
    __shared__ unsigned wtot[4];
    if (lane == 63) wtot[wave] = incl;
    __syncthreads();
    unsigned pre = 0;
    for (int w = 0; w < wave; w++) pre += wtot[w];
    unsigned excl = pre + incl - sum;
    unsigned run = excl;
    #pragma unroll
    for (int q = 0; q < 40; q++) {
        int idx = tid*40 + q;
        if (idx < 10000) { offs[idx] = run; run += lc[q]; }
    }
    if (tid == 255) {
        offs[10000] = excl;   // == grand total (threads 250..255 contribute 0)
        const float DEGc = 57.29577951308232f;
        float th = poses_last[2] / DEGc;
        float s = sinf(th), c = cosf(th);
        float ny = poses_last[1] + pose_obs[0]*s + pose_obs[1]*c;
        float nx = poses_last[0] + pose_obs[0]*c - pose_obs[1]*s;
        float nt = poses_last[2] + pose_obs[2]*DEGc;
        nt = fmodf(nt - 180.0f, 360.0f) + 180.0f;
        nt = fmodf(nt + 180.0f, 360.0f) - 180.0f;
        out_pose[0] = nx; out_pose[1] = ny; out_pose[2] = nt;
        out_pose[3] = nx; out_pose[4] = ny; out_pose[5] = nt;
        float sx = -((nx*100.0f)/5.0f - 480.0f)/480.0f;
        float sy = -((ny*100.0f)/5.0f - 480.0f)/480.0f;
        float sth = ((90.0f - nt) * 3.14159265358979323846f) / 180.0f;
        scal[0] = cosf(sth);
        scal[1] = sinf(sth);
        scal[2] = sx;
        scal[3] = sy;
    }
}

// ---------------- scatter (atomic-free slot write, 1 px/thread) + ks ----------------
__global__ __launch_bounds__(256) void scatter_kernel(const float* __restrict__ obs,
                                                      const unsigned* __restrict__ offs,
                                                      const unsigned* __restrict__ pack,
                                                      float4* __restrict__ pos,
                                                      float4* __restrict__ feat,
                                                      float* scal, float fcam) {
    int p = blockIdx.x*256 + threadIdx.x;
    int i = p / 640, j = p - i*640;
    unsigned pk = pack[p];
    float d  = obs[3*NPIX + p];
    float f1 = obs[4*NPIX + p];
    float f2 = obs[5*NPIX + p];
    float f3 = obs[6*NPIX + p];
    float f4 = obs[7*NPIX + p];
    float f5 = obs[8*NPIX + p];
    if (pk != 0xFFFFFFFFu) {
        unsigned b = pk / PACK_M;
        unsigned rank = pk - b * PACK_M;
        unsigned k = offs[b] + rank;
        float X = ((float)j - 319.5f) * d / fcam + 250.0f;
        float Z = ((float)(479 - i) - 239.5f) * d / fcam + 88.0f;
        float xs = ((X/5.0f - 50.0f)/100.0f)*2.0f;
        float ys = ((d/5.0f - 50.0f)/100.0f)*2.0f;
        float zs = ((Z/5.0f - 32.0f)/80.0f)*2.0f;
        float pos0 = (xs*100.0f)/2.0f + 50.0f;
        float pos1 = (ys*100.0f)/2.0f + 50.0f;
        float pos2 = (zs*80.0f)/2.0f + 40.0f;
        pos[k]  = make_float4(pos0, pos1, pos2, f1);
        feat[k] = make_float4(f2, f3, f4, f5);
    }
    // ks channel maxima (obs values nonnegative), block-level reduce
    float m0 = f1, m1 = f2, m2 = f3, m3 = f4;
    #pragma unroll
    for (int off = 32; off > 0; off >>= 1) {
        m0 = fmaxf(m0, __shfl_down(m0, off, 64));
        m1 = fmaxf(m1, __shfl_down(m1, off, 64));
        m2 = fmaxf(m2, __shfl_down(m2, off, 64));
        m3 = fmaxf(m3, __shfl_down(m3, off, 64));
    }
    __shared__ float red[4][4];
    int lane = threadIdx.x & 63, wave = threadIdx.x >> 6;
    if (lane == 0) {
        red[wave][0] = m0; red[wave][1] = m1; red[wave][2] = m2; red[wave][3] = m3;
    }
    __syncthreads();
    if (threadIdx.x < 4) {
        int c = threadIdx.x;
        float m = fmaxf(fmaxf(red[0][c], red[1][c]), fmaxf(red[2][c], red[3][c]));
        atomicMax((int*)&scal[16*(c+1)], __float_as_int(m));  // slots 16/32/48/64: separate lines
    }
}

// ---------------- gather: 2500 WGs x 256 thr; 1 wave = 1 corner column ----------------
// R2-proven math (per-wave LDS slab, 488 stride). Two changes vs R2:
// (1) merged-segment coalesced indexing: lane -> consecutive k, so each wave's pos
//     fetches are contiguous ~2KB runs;
// (2) heavy-first scheduling: x-groups ordered by distance from the center pileup
//     (x ~ 50 columns carry ~10x the points), so the longest waves start first
//     instead of defining the tail.
__global__ __launch_bounds__(256) void gather_kernel(const float4* __restrict__ pos,
                                                     const float4* __restrict__ feat,
                                                     const unsigned* __restrict__ offs,
                                                     float* __restrict__ sm,
                                                     float* __restrict__ out_fp) {
    int wave = threadIdx.x >> 6, lane = threadIdx.x & 63;
    int y  = blockIdx.x / 25;          // corner-y 0..99
    int gi = blockIdx.x % 25;          // launch-order x-group
    int xg = (gi == 0) ? 12 : ((gi & 1) ? (12 + (gi+1)/2) : (12 - gi/2));  // bijection on [0,25)
    int x = xg*4 + wave;               // corner-x 0..99
    __shared__ float slabs[4][488];
    float* za = slabs[wave];
    for (int q = lane; q < 480; q += 64) za[q] = 0.0f;
    __syncthreads();
    if (x >= 1 && y >= 1) {            // x==0 or y==0: no in-bounds corners (safe=0)
        int b0 = (x-1)*100 + (y-1);    // bins (x-1,y-1),(x-1,y) contiguous
        int b1 = x*100 + (y-1);        // bins (x,y-1),(x,y) contiguous
        unsigned s0 = offs[b0], e0 = offs[b0+2];
        unsigned s1 = offs[b1], e1 = offs[b1+2];
        unsigned n0 = e0 - s0, n = n0 + (e1 - s1);
        float xf = (float)x, yf = (float)y;
        for (unsigned idx = lane; idx < n; idx += 64) {
            unsigned k = (idx < n0) ? (s0 + idx) : (s1 + idx - n0);
            float4 a = pos[k];
            // weights replicate reference order: ((1*(1-|d0|))*(1-|d1|))*(1-|d2|)
            float w0 = 1.0f - fabsf(a.x - xf);
            float w1 = 1.0f - fabsf(a.y - yf);
            float w01 = w0 * w1;
            float bzf = floorf(a.z);
            bool need = (bzf >= 12.0f) && (bzf < 25.0f);
            float4 q2 = need ? feat[k] : make_float4(0.f, 0.f, 0.f, 0.f);
            #pragma unroll
            for (int c2 = 0; c2 <= 1; c2++) {
                float p2 = bzf + (float)c2;
                if (!(p2 > 0.0f && p2 < 80.0f)) continue;
                float w = w01 * (1.0f - fabsf(a.z - p2));
                int zi = (int)p2;
                int zb = zi * 6;
                atomicAdd(&za[zb + 0], w);
                if (zi >= 13 && zi < 25) {
                    atomicAdd(&za[zb + 1], w*a.w);
                    atomicAdd(&za[zb + 2], w*q2.x);
                    atomicAdd(&za[zb + 3], w*q2.y);
                    atomicAdd(&za[zb + 4], w*q2.z);
                    atomicAdd(&za[zb + 5], w*q2.w);
                }
            }
        }
    }
    __syncthreads();
    // per-z round, then column sums (exact: summands are small integers)
    int z = lane;                      // z in [0,64); [64,80) folded by lanes 0..15
    float r0 = rintf(za[z*6 + 0]);
    float all0 = r0;
    if (lane < 16) all0 += rintf(za[(z + 64)*6 + 0]);
    bool inb = (z >= 13 && z < 25);
    float a0 = inb ? r0 : 0.0f;
    float a1 = inb ? rintf(za[z*6 + 1]) : 0.0f;
    float a2 = inb ? rintf(za[z*6 + 2]) : 0.0f;
    float a3 = inb ? rintf(za[z*6 + 3]) : 0.0f;
    float a4 = inb ? rintf(za[z*6 + 4]) : 0.0f;
    float a5 = inb ? rintf(za[z*6 + 5]) : 0.0f;
    #pragma unroll
    for (int off = 32; off > 0; off >>= 1) {
        all0 += __shfl_down(all0, off, 64);
        a0 += __shfl_down(a0, off, 64);
        a1 += __shfl_down(a1, off, 64);
        a2 += __shfl_down(a2, off, 64);
        a3 += __shfl_down(a3, off, 64);
        a4 += __shfl_down(a4, off, 64);
        a5 += __shfl_down(a5, off, 64);
    }
    if (lane == 0) {
        int t = y*100 + x;
        float fp = fminf(a0, 1.0f);
        float ex = fminf(all0, 1.0f);
        sm[0*10000 + t] = fp;
        sm[1*10000 + t] = ex;
        sm[2*10000 + t] = fminf(a1/5.0f, 1.0f);
        sm[3*10000 + t] = fminf(a2/5.0f, 1.0f);
        sm[4*10000 + t] = fminf(a3/5.0f, 1.0f);
        sm[5*10000 + t] = fminf(a4/5.0f, 1.0f);
        sm[6*10000 + t] = fminf(a5/5.0f, 1.0f);
        out_fp[t] = fp;
    }
}

// bilinear sample of the (implicit, mostly-zero) agent_view at normalized coords
__device__ __forceinline__ void sample_agent(float gxv, float gyv,
                                             float ct, float sn,
                                             const float* __restrict__ sm,
                                             float rot[7]) {
    float u = ct*gxv - sn*gyv;
    float v = sn*gxv + ct*gyv;
    float xim = ((u + 1.0f)*0.5f)*959.0f;
    float yim = ((v + 1.0f)*0.5f)*959.0f;
    float x0 = floorf(xim), y0 = floorf(yim);
    #pragma unroll
    for (int ty = 0; ty <= 1; ty++) {
        float yy = y0 + (float)ty;
        if (yy < 480.0f || yy >= 580.0f) continue;   // region rows [480,580)
        float wy = 1.0f - fabsf(yim - yy);
        int yi = (int)yy - 480;
        #pragma unroll
        for (int tx = 0; tx <= 1; tx++) {
            float xx = x0 + (float)tx;
            if (xx < 430.0f || xx >= 530.0f) continue;  // region cols [430,530)
            float w = (1.0f - fabsf(xim - xx)) * wy;
            int o = yi*100 + ((int)xx - 430);
            #pragma unroll
            for (int k = 0; k < 7; k++) rot[k] += sm[k*10000 + o] * w;
        }
    }
}

__device__ __forceinline__ void pixel_ts(float xim, float yim, float ct, float sn,
                                         const float* __restrict__ sm, float ts[7]) {
    const float step = 2.0f/959.0f;
    float x0 = floorf(xim), y0 = floorf(yim);
    #pragma unroll
    for (int ty = 0; ty <= 1; ty++) {
        float yy = y0 + (float)ty;
        if (yy < 0.0f || yy > 959.0f) continue;
        float wy = 1.0f - fabsf(yim - yy);
        #pragma unroll
        for (int tx = 0; tx <= 1; tx++) {
            float xx = x0 + (float)tx;
            if (xx < 0.0f || xx > 959.0f) continue;
            float w = (1.0f - fabsf(xim - xx)) * wy;
            float rot[7] = {0,0,0,0,0,0,0};
            float gx1 = xx*step - 1.0f;
            float gy1 = yy*step - 1.0f;
            sample_agent(gx1, gy1, ct, sn, sm, rot);
            #pragma unroll
            for (int k = 0; k < 7; k++) ts[k] += rot[k]*w;
        }
    }
}

// ---------------- final: 4 px/thread, float4 fast path ----------------
__global__ __launch_bounds__(256) void final_kernel(const float* __restrict__ maps_last,
                                                    const float* __restrict__ sm,
                                                    const float* __restrict__ scal,
                                                    float* __restrict__ out_map) {
    int g = blockIdx.x*256 + threadIdx.x;    // 0..230399
    int p = g*4;
    int y = p / MDIM, xp = p - y*MDIM;       // 4 pixels share a row (960%4==0)
    float ct = scal[0], sn = scal[1], sx = scal[2], sy = scal[3];
    const float step = 2.0f/959.0f;
    float gyv = (float)y*step - 1.0f;
    float v = gyv + sy;
    float yim = ((v + 1.0f)*0.5f)*959.0f;
    float gyc = yim*step - 1.0f;
    float xims[4];
    bool act[4];
    bool any = false;
    #pragma unroll
    for (int q = 0; q < 4; q++) {
        float gxv = (float)(xp+q)*step - 1.0f;
        float u = gxv + sx;
        float xim = ((u + 1.0f)*0.5f)*959.0f;
        xims[q] = xim;
        // Early reject: rotation is an isometry; the 4 translation taps lie
        // within sqrt(2) px of the rotated center; >1.5 px outside the active
        // window (rows (479,580), cols (429,530)) -> every sample exactly 0.
        float gxc = xim*step - 1.0f;
        float uc = ct*gxc - sn*gyc;
        float vc = sn*gxc + ct*gyc;
        float xc2 = ((uc + 1.0f)*0.5f)*959.0f;
        float yc2 = ((vc + 1.0f)*0.5f)*959.0f;
        bool a = (xc2 > 427.5f) && (xc2 < 531.5f) && (yc2 > 477.5f) && (yc2 < 581.5f);
        act[q] = a;
        any = any || a;
    }
    if (!any) {
        // ts == 0 exactly for all 4 pixels: every channel -> max(ml, 0)
        #pragma unroll
        for (int c = 0; c < 9; c++) {
            float4 ml = *(const float4*)(maps_last + c*MPIX + p);
            float4 o;
            o.x = fmaxf(ml.x, 0.0f); o.y = fmaxf(ml.y, 0.0f);
            o.z = fmaxf(ml.z, 0.0f); o.w = fmaxf(ml.w, 0.0f);
            *(float4*)(out_map + c*MPIX + p) = o;
        }
        return;
    }
    float ks0 = scal[16], ks1 = scal[32], ks2 = scal[48], ks3 = scal[64];
    #pragma unroll
    for (int q = 0; q < 4; q++) {
        int o = p + q;
        float ts[7] = {0,0,0,0,0,0,0};
        if (act[q]) pixel_ts(xims[q], yim, ct, sn, sm, ts);
        float ml;
        ml = maps_last[0*MPIX + o]; out_map[0*MPIX + o] = fmaxf(ml, ts[0]);
        ml = maps_last[1*MPIX + o]; out_map[1*MPIX + o] = fmaxf(ml, ts[1]);
        ml = maps_last[2*MPIX + o]; out_map[2*MPIX + o] = fmaxf(ml, 0.0f);
        ml = maps_last[3*MPIX + o]; out_map[3*MPIX + o] = fmaxf(ml, 0.0f);
        float t4 = ts[2]; t4 = (t4 > 0.0f) ? ks0 : t4;
        ml = maps_last[4*MPIX + o]; out_map[4*MPIX + o] = fmaxf(ml, t4);
        float t5 = ts[3]; t5 = (t5 > 0.0f) ? ks1 : t5;
        ml = maps_last[5*MPIX + o]; out_map[5*MPIX + o] = fmaxf(ml, t5);
        float t6 = ts[4]; t6 = (t6 > 0.0f) ? ks2 : t6;
        ml = maps_last[6*MPIX + o]; out_map[6*MPIX + o] = fmaxf(ml, t6);
        float t7 = ts[5]; t7 = (t7 > 0.0f) ? ks3 : t7;
        ml = maps_last[7*MPIX + o]; out_map[7*MPIX + o] = fmaxf(ml, t7);
        ml = maps_last[8*MPIX + o]; out_map[8*MPIX + o] = fmaxf(ml, ts[6]);
    }
}

extern "C" void kernel_launch(void* const* d_in, const int* in_sizes, int n_in,
                              void* d_out, int out_size, void* d_ws, size_t ws_size,
                              hipStream_t stream) {
    const float* obs        = (const float*)d_in[0];
    const float* pose_obs   = (const float*)d_in[1];
    const float* maps_last  = (const float*)d_in[2];
    const float* poses_last = (const float*)d_in[3];
    float* out = (float*)d_out;

    unsigned* ws_u = (unsigned*)d_ws;
    float*    ws_f = (float*)d_ws;
    float*    scal = ws_f + SCAL_OFF;
    unsigned* offs = ws_u + OFFS_OFF;
    float*    sm   = ws_f + SM_OFF;
    unsigned* pack = ws_u + PACK_OFF;
    float4*   pos  = (float4*)(ws_f + POS_OFF);
    float4*   feat = (float4*)(ws_f + FEAT_OFF);
    unsigned* cnt  = ws_u + POS_OFF;   // aliases pos head; dead before scatter writes

    // single memset: cnt only (1.28MB; scal ks slots zeroed inside scan_pose)
    hipMemsetAsync(ws_f + POS_OFF, 0, (size_t)10000 * CNT_STRIDE * 4u, stream);

    float fcam = (float)(320.0 / tan(39.5 * M_PI / 180.0));

    count_kernel<<<1200, 256, 0, stream>>>(obs, cnt, pack, fcam);
    scan_pose_kernel<<<1, 256, 0, stream>>>(cnt, offs, pose_obs, poses_last,
                                            scal, out + OUT_POSE);
    scatter_kernel<<<1200, 256, 0, stream>>>(obs, offs, pack, pos, feat, scal, fcam);
    gather_kernel<<<2500, 256, 0, stream>>>(pos, feat, offs, sm, out + OUT_FPMAP);
    final_kernel<<<900, 256, 0, stream>>>(maps_last, sm, scal, out + OUT_MAP);
}

// Round 10
// 223.127 us; speedup vs baseline: 6.5961x; 1.1150x over previous
//
#include <hip/hip_runtime.h>
#include <math.h>

#define NPIX (480*640)
#define MDIM 960
#define MPIX (MDIM*MDIM)
#define PACK_M 307201u
#define CNT_STRIDE 32   // one 128B line per bin (atomic contention spread)

// ws layout (u32/f32 units from base)
#define SCAL_OFF 0        // f32[80]: [0..3] pose-derived, ks at 16/32/48/64 (separate lines)
#define OFFS_OFF 80       // u32[10001]
#define SM_OFF   10084    // f32[70000]: 7 planes * 10000
#define PACK_OFF 80084    // u32[NPIX]
#define POS_OFF  387284   // f32[4*NPIX]; byte offset % 16 == 0
#define FEAT_OFF 1616084  // f32[4*NPIX]; byte offset % 16 == 0
// cnt (u32, stride 32, 10000 bins = 1.28MB) ALIASES the start of pos:
// it is fully consumed by scan_pose before scatter writes pos.

// output layout (floats)
#define OUT_FPMAP 0
#define OUT_MAP   10000
#define OUT_POSE  (10000 + 9*MPIX)

typedef float __attribute__((ext_vector_type(4))) f32x4;
__device__ __forceinline__ f32x4 ntload4(const float* p) {
    return __builtin_nontemporal_load((const f32x4*)p);
}
__device__ __forceinline__ void ntstore4(float* p, f32x4 v) {
    __builtin_nontemporal_store(v, (f32x4*)p);
}

// ---------------- count (1 px/thread, bins spread 1 line apart) ----------------
__global__ __launch_bounds__(256) void count_kernel(const float* __restrict__ obs,
                                                    unsigned* __restrict__ cnt,
                                                    unsigned* __restrict__ pack,
                                                    float fcam) {
    int p = blockIdx.x*256 + threadIdx.x;          // 0..307199
    int i = p / 640, j = p - i*640;
    float d = obs[3*NPIX + p];
    float X = ((float)j - 319.5f) * d / fcam + 250.0f;
    float Z = ((float)(479 - i) - 239.5f) * d / fcam + 88.0f;
    float xs = ((X/5.0f - 50.0f)/100.0f)*2.0f;
    float ys = ((d/5.0f - 50.0f)/100.0f)*2.0f;
    float zs = ((Z/5.0f - 32.0f)/80.0f)*2.0f;
    float pos0 = (xs*100.0f)/2.0f + 50.0f;
    float pos1 = (ys*100.0f)/2.0f + 50.0f;
    float pos2 = (zs*80.0f)/2.0f + 40.0f;
    int bx = (int)floorf(pos0), by = (int)floorf(pos1), bz = (int)floorf(pos2);
    unsigned pk = 0xFFFFFFFFu;
    if (bx >= 0 && bx <= 99 && by >= 0 && by <= 99 && bz >= 0 && bz <= 79) {
        unsigned b = (unsigned)(bx*100 + by);
        unsigned rank = atomicAdd(&cnt[b*CNT_STRIDE], 1u);
        pk = b * PACK_M + rank;
    }
    pack[p] = pk;
}

// ---------------- scan (256 threads, one WG) + pose fused; zeroes ks slots ----------------
__global__ __launch_bounds__(256) void scan_pose_kernel(const unsigned* __restrict__ cnt,
                                                        unsigned* __restrict__ offs,
                                                        const float* pose_obs,
                                                        const float* poses_last,
                                                        float* scal, float* out_pose) {
    int tid = threadIdx.x;
    int lane = tid & 63, wave = tid >> 6;
    // zero the ks atomicMax targets (scatter, which runs next, maxes into them)
    if (tid < 4) scal[16*(tid+1)] = 0.0f;
    unsigned lc[40];
    unsigned sum = 0;
    #pragma unroll
    for (int q = 0; q < 40; q++) {
        int idx = tid*40 + q;
        lc[q] = (idx < 10000) ? cnt[idx*CNT_STRIDE] : 0u;
        sum += lc[q];
    }
    unsigned incl = sum;
    #pragma unroll
    for (int off = 1; off < 64; off <<= 1) {
        unsigned u = (unsigned)__shfl_up((int)incl, off, 64);
        if (lane >= off) incl += u;
    }
    __shared__ unsigned wtot[4];
    if (lane == 63) wtot[wave] = incl;
    __syncthreads();
    unsigned pre = 0;
    for (int w = 0; w < wave; w++) pre += wtot[w];
    unsigned excl = pre + incl - sum;
    unsigned run = excl;
    #pragma unroll
    for (int q = 0; q < 40; q++) {
        int idx = tid*40 + q;
        if (idx < 10000) { offs[idx] = run; run += lc[q]; }
    }
    if (tid == 255) {
        offs[10000] = excl;   // == grand total (threads 250..255 contribute 0)
        const float DEGc = 57.29577951308232f;
        float th = poses_last[2] / DEGc;
        float s = sinf(th), c = cosf(th);
        float ny = poses_last[1] + pose_obs[0]*s + pose_obs[1]*c;
        float nx = poses_last[0] + pose_obs[0]*c - pose_obs[1]*s;
        float nt = poses_last[2] + pose_obs[2]*DEGc;
        nt = fmodf(nt - 180.0f, 360.0f) + 180.0f;
        nt = fmodf(nt + 180.0f, 360.0f) - 180.0f;
        out_pose[0] = nx; out_pose[1] = ny; out_pose[2] = nt;
        out_pose[3] = nx; out_pose[4] = ny; out_pose[5] = nt;
        float sx = -((nx*100.0f)/5.0f - 480.0f)/480.0f;
        float sy = -((ny*100.0f)/5.0f - 480.0f)/480.0f;
        float sth = ((90.0f - nt) * 3.14159265358979323846f) / 180.0f;
        scal[0] = cosf(sth);
        scal[1] = sinf(sth);
        scal[2] = sx;
        scal[3] = sy;
    }
}

// ---------------- scatter (atomic-free slot write, 1 px/thread) + ks ----------------
__global__ __launch_bounds__(256) void scatter_kernel(const float* __restrict__ obs,
                                                      const unsigned* __restrict__ offs,
                                                      const unsigned* __restrict__ pack,
                                                      float4* __restrict__ pos,
                                                      float4* __restrict__ feat,
                                                      float* scal, float fcam) {
    int p = blockIdx.x*256 + threadIdx.x;
    int i = p / 640, j = p - i*640;
    unsigned pk = pack[p];
    float d  = obs[3*NPIX + p];
    float f1 = obs[4*NPIX + p];
    float f2 = obs[5*NPIX + p];
    float f3 = obs[6*NPIX + p];
    float f4 = obs[7*NPIX + p];
    float f5 = obs[8*NPIX + p];
    if (pk != 0xFFFFFFFFu) {
        unsigned b = pk / PACK_M;
        unsigned rank = pk - b * PACK_M;
        unsigned k = offs[b] + rank;
        float X = ((float)j - 319.5f) * d / fcam + 250.0f;
        float Z = ((float)(479 - i) - 239.5f) * d / fcam + 88.0f;
        float xs = ((X/5.0f - 50.0f)/100.0f)*2.0f;
        float ys = ((d/5.0f - 50.0f)/100.0f)*2.0f;
        float zs = ((Z/5.0f - 32.0f)/80.0f)*2.0f;
        float pos0 = (xs*100.0f)/2.0f + 50.0f;
        float pos1 = (ys*100.0f)/2.0f + 50.0f;
        float pos2 = (zs*80.0f)/2.0f + 40.0f;
        pos[k]  = make_float4(pos0, pos1, pos2, f1);
        feat[k] = make_float4(f2, f3, f4, f5);
    }
    // ks channel maxima (obs values nonnegative), block-level reduce
    float m0 = f1, m1 = f2, m2 = f3, m3 = f4;
    #pragma unroll
    for (int off = 32; off > 0; off >>= 1) {
        m0 = fmaxf(m0, __shfl_down(m0, off, 64));
        m1 = fmaxf(m1, __shfl_down(m1, off, 64));
        m2 = fmaxf(m2, __shfl_down(m2, off, 64));
        m3 = fmaxf(m3, __shfl_down(m3, off, 64));
    }
    __shared__ float red[4][4];
    int lane = threadIdx.x & 63, wave = threadIdx.x >> 6;
    if (lane == 0) {
        red[wave][0] = m0; red[wave][1] = m1; red[wave][2] = m2; red[wave][3] = m3;
    }
    __syncthreads();
    if (threadIdx.x < 4) {
        int c = threadIdx.x;
        float m = fmaxf(fmaxf(red[0][c], red[1][c]), fmaxf(red[2][c], red[3][c]));
        atomicMax((int*)&scal[16*(c+1)], __float_as_int(m));  // slots 16/32/48/64: separate lines
    }
}

// ---------------- gather: 10000 WGs; 1 block = 1 corner column, 4 waves split points ----------------
// Fixes vs R9 (both mechanism-targeted):
// (1) the fat center columns (~4-8x mean points) previously ran on ONE wave and set the
//     kernel tail (avg occupancy 35%). Now the block's 4 waves each stream a quarter of
//     the column's merged segments into a PRIVATE LDS slab; a 480-entry combine sums the
//     4 slabs before the rint-reduce. Critical path of the fattest column drops ~4x.
// (2) feat[k] is loaded UNCONDITIONALLY next to pos[k] — the old `need` gate made it a
//     dependent load (two serial ~900cy latencies per iteration); now both overlap.
__global__ __launch_bounds__(256) void gather_kernel(const float4* __restrict__ pos,
                                                     const float4* __restrict__ feat,
                                                     const unsigned* __restrict__ offs,
                                                     float* __restrict__ sm,
                                                     float* __restrict__ out_fp) {
    int wave = threadIdx.x >> 6, lane = threadIdx.x & 63;
    int x = blockIdx.x % 100, y = blockIdx.x / 100;   // corner column (x,y); t == blockIdx.x
    __shared__ float slabs[4][488];                   // per-wave private; 488 stride pads banks
    float* za = slabs[wave];
    for (int q = lane; q < 480; q += 64) za[q] = 0.0f;
    __syncthreads();
    if (x >= 1 && y >= 1) {            // x==0 or y==0: no in-bounds corners (safe=0)
        int b0 = (x-1)*100 + (y-1);    // bins (x-1,y-1),(x-1,y) contiguous
        int b1 = x*100 + (y-1);        // bins (x,y-1),(x,y) contiguous
        unsigned s0 = offs[b0], e0 = offs[b0+2];
        unsigned s1 = offs[b1], e1 = offs[b1+2];
        unsigned n0 = e0 - s0, n = n0 + (e1 - s1);
        float xf = (float)x, yf = (float)y;
        for (unsigned idx = threadIdx.x; idx < n; idx += 256) {
            unsigned k = (idx < n0) ? (s0 + idx) : (s1 + idx - n0);
            float4 a  = pos[k];
            float4 q2 = feat[k];       // unconditional: overlaps with pos load
            // weights replicate reference order: ((1*(1-|d0|))*(1-|d1|))*(1-|d2|)
            float w0 = 1.0f - fabsf(a.x - xf);
            float w1 = 1.0f - fabsf(a.y - yf);
            float w01 = w0 * w1;
            float bzf = floorf(a.z);
            #pragma unroll
            for (int c2 = 0; c2 <= 1; c2++) {
                float p2 = bzf + (float)c2;
                if (!(p2 > 0.0f && p2 < 80.0f)) continue;
                float w = w01 * (1.0f - fabsf(a.z - p2));
                int zi = (int)p2;
                int zb = zi * 6;
                atomicAdd(&za[zb + 0], w);
                if (zi >= 13 && zi < 25) {
                    atomicAdd(&za[zb + 1], w*a.w);
                    atomicAdd(&za[zb + 2], w*q2.x);
                    atomicAdd(&za[zb + 3], w*q2.y);
                    atomicAdd(&za[zb + 4], w*q2.z);
                    atomicAdd(&za[zb + 5], w*q2.w);
                }
            }
        }
    }
    __syncthreads();
    // combine the 4 per-wave slabs
    for (int q = threadIdx.x; q < 480; q += 256) {
        slabs[0][q] = slabs[0][q] + slabs[1][q] + slabs[2][q] + slabs[3][q];
    }
    __syncthreads();
    if (wave == 0) {
        // per-z round, then column sums (exact: summands are small integers)
        int z = lane;                  // z in [0,64); [64,80) folded by lanes 0..15
        float r0 = rintf(slabs[0][z*6 + 0]);
        float all0 = r0;
        if (lane < 16) all0 += rintf(slabs[0][(z + 64)*6 + 0]);
        bool inb = (z >= 13 && z < 25);
        float a0 = inb ? r0 : 0.0f;
        float a1 = inb ? rintf(slabs[0][z*6 + 1]) : 0.0f;
        float a2 = inb ? rintf(slabs[0][z*6 + 2]) : 0.0f;
        float a3 = inb ? rintf(slabs[0][z*6 + 3]) : 0.0f;
        float a4 = inb ? rintf(slabs[0][z*6 + 4]) : 0.0f;
        float a5 = inb ? rintf(slabs[0][z*6 + 5]) : 0.0f;
        #pragma unroll
        for (int off = 32; off > 0; off >>= 1) {
            all0 += __shfl_down(all0, off, 64);
            a0 += __shfl_down(a0, off, 64);
            a1 += __shfl_down(a1, off, 64);
            a2 += __shfl_down(a2, off, 64);
            a3 += __shfl_down(a3, off, 64);
            a4 += __shfl_down(a4, off, 64);
            a5 += __shfl_down(a5, off, 64);
        }
        if (lane == 0) {
            int t = y*100 + x;
            float fp = fminf(a0, 1.0f);
            float ex = fminf(all0, 1.0f);
            sm[0*10000 + t] = fp;
            sm[1*10000 + t] = ex;
            sm[2*10000 + t] = fminf(a1/5.0f, 1.0f);
            sm[3*10000 + t] = fminf(a2/5.0f, 1.0f);
            sm[4*10000 + t] = fminf(a3/5.0f, 1.0f);
            sm[5*10000 + t] = fminf(a4/5.0f, 1.0f);
            sm[6*10000 + t] = fminf(a5/5.0f, 1.0f);
            out_fp[t] = fp;
        }
    }
}

// bilinear sample of the (implicit, mostly-zero) agent_view at normalized coords
__device__ __forceinline__ void sample_agent(float gxv, float gyv,
                                             float ct, float sn,
                                             const float* __restrict__ sm,
                                             float rot[7]) {
    float u = ct*gxv - sn*gyv;
    float v = sn*gxv + ct*gyv;
    float xim = ((u + 1.0f)*0.5f)*959.0f;
    float yim = ((v + 1.0f)*0.5f)*959.0f;
    float x0 = floorf(xim), y0 = floorf(yim);
    #pragma unroll
    for (int ty = 0; ty <= 1; ty++) {
        float yy = y0 + (float)ty;
        if (yy < 480.0f || yy >= 580.0f) continue;   // region rows [480,580)
        float wy = 1.0f - fabsf(yim - yy);
        int yi = (int)yy - 480;
        #pragma unroll
        for (int tx = 0; tx <= 1; tx++) {
            float xx = x0 + (float)tx;
            if (xx < 430.0f || xx >= 530.0f) continue;  // region cols [430,530)
            float w = (1.0f - fabsf(xim - xx)) * wy;
            int o = yi*100 + ((int)xx - 430);
            #pragma unroll
            for (int k = 0; k < 7; k++) rot[k] += sm[k*10000 + o] * w;
        }
    }
}

__device__ __forceinline__ void pixel_ts(float xim, float yim, float ct, float sn,
                                         const float* __restrict__ sm, float ts[7]) {
    const float step = 2.0f/959.0f;
    float x0 = floorf(xim), y0 = floorf(yim);
    #pragma unroll
    for (int ty = 0; ty <= 1; ty++) {
        float yy = y0 + (float)ty;
        if (yy < 0.0f || yy > 959.0f) continue;
        float wy = 1.0f - fabsf(yim - yy);
        #pragma unroll
        for (int tx = 0; tx <= 1; tx++) {
            float xx = x0 + (float)tx;
            if (xx < 0.0f || xx > 959.0f) continue;
            float w = (1.0f - fabsf(xim - xx)) * wy;
            float rot[7] = {0,0,0,0,0,0,0};
            float gx1 = xx*step - 1.0f;
            float gy1 = yy*step - 1.0f;
            sample_agent(gx1, gy1, ct, sn, sm, rot);
            #pragma unroll
            for (int k = 0; k < 7; k++) ts[k] += rot[k]*w;
        }
    }
}

// ---------------- final: 4 px/thread; non-temporal float4 streaming fast path ----------------
__global__ __launch_bounds__(256) void final_kernel(const float* __restrict__ maps_last,
                                                    const float* __restrict__ sm,
                                                    const float* __restrict__ scal,
                                                    float* __restrict__ out_map) {
    int g = blockIdx.x*256 + threadIdx.x;    // 0..230399
    int p = g*4;
    int y = p / MDIM, xp = p - y*MDIM;       // 4 pixels share a row (960%4==0)
    float ct = scal[0], sn = scal[1], sx = scal[2], sy = scal[3];
    const float step = 2.0f/959.0f;
    float gyv = (float)y*step - 1.0f;
    float v = gyv + sy;
    float yim = ((v + 1.0f)*0.5f)*959.0f;
    float gyc = yim*step - 1.0f;
    float xims[4];
    bool act[4];
    bool any = false;
    #pragma unroll
    for (int q = 0; q < 4; q++) {
        float gxv = (float)(xp+q)*step - 1.0f;
        float u = gxv + sx;
        float xim = ((u + 1.0f)*0.5f)*959.0f;
        xims[q] = xim;
        // Early reject: rotation is an isometry; the 4 translation taps lie
        // within sqrt(2) px of the rotated center; >1.5 px outside the active
        // window (rows (479,580), cols (429,530)) -> every sample exactly 0.
        float gxc = xim*step - 1.0f;
        float uc = ct*gxc - sn*gyc;
        float vc = sn*gxc + ct*gyc;
        float xc2 = ((uc + 1.0f)*0.5f)*959.0f;
        float yc2 = ((vc + 1.0f)*0.5f)*959.0f;
        bool a = (xc2 > 427.5f) && (xc2 < 531.5f) && (yc2 > 477.5f) && (yc2 < 581.5f);
        act[q] = a;
        any = any || a;
    }
    if (!any) {
        // ts == 0 exactly for all 4 pixels: every channel -> max(ml, 0).
        // Pure 66MB stream: non-temporal avoids L2 write-allocate/pollution.
        #pragma unroll
        for (int c = 0; c < 9; c++) {
            f32x4 ml = ntload4(maps_last + c*MPIX + p);
            f32x4 o;
            o.x = fmaxf(ml.x, 0.0f); o.y = fmaxf(ml.y, 0.0f);
            o.z = fmaxf(ml.z, 0.0f); o.w = fmaxf(ml.w, 0.0f);
            ntstore4(out_map + c*MPIX + p, o);
        }
        return;
    }
    float ks0 = scal[16], ks1 = scal[32], ks2 = scal[48], ks3 = scal[64];
    #pragma unroll
    for (int q = 0; q < 4; q++) {
        int o = p + q;
        float ts[7] = {0,0,0,0,0,0,0};
        if (act[q]) pixel_ts(xims[q], yim, ct, sn, sm, ts);
        float ml;
        ml = maps_last[0*MPIX + o]; out_map[0*MPIX + o] = fmaxf(ml, ts[0]);
        ml = maps_last[1*MPIX + o]; out_map[1*MPIX + o] = fmaxf(ml, ts[1]);
        ml = maps_last[2*MPIX + o]; out_map[2*MPIX + o] = fmaxf(ml, 0.0f);
        ml = maps_last[3*MPIX + o]; out_map[3*MPIX + o] = fmaxf(ml, 0.0f);
        float t4 = ts[2]; t4 = (t4 > 0.0f) ? ks0 : t4;
        ml = maps_last[4*MPIX + o]; out_map[4*MPIX + o] = fmaxf(ml, t4);
        float t5 = ts[3]; t5 = (t5 > 0.0f) ? ks1 : t5;
        ml = maps_last[5*MPIX + o]; out_map[5*MPIX + o] = fmaxf(ml, t5);
        float t6 = ts[4]; t6 = (t6 > 0.0f) ? ks2 : t6;
        ml = maps_last[6*MPIX + o]; out_map[6*MPIX + o] = fmaxf(ml, t6);
        float t7 = ts[5]; t7 = (t7 > 0.0f) ? ks3 : t7;
        ml = maps_last[7*MPIX + o]; out_map[7*MPIX + o] = fmaxf(ml, t7);
        ml = maps_last[8*MPIX + o]; out_map[8*MPIX + o] = fmaxf(ml, ts[6]);
    }
}

extern "C" void kernel_launch(void* const* d_in, const int* in_sizes, int n_in,
                              void* d_out, int out_size, void* d_ws, size_t ws_size,
                              hipStream_t stream) {
    const float* obs        = (const float*)d_in[0];
    const float* pose_obs   = (const float*)d_in[1];
    const float* maps_last  = (const float*)d_in[2];
    const float* poses_last = (const float*)d_in[3];
    float* out = (float*)d_out;

    unsigned* ws_u = (unsigned*)d_ws;
    float*    ws_f = (float*)d_ws;
    float*    scal = ws_f + SCAL_OFF;
    unsigned* offs = ws_u + OFFS_OFF;
    float*    sm   = ws_f + SM_OFF;
    unsigned* pack = ws_u + PACK_OFF;
    float4*   pos  = (float4*)(ws_f + POS_OFF);
    float4*   feat = (float4*)(ws_f + FEAT_OFF);
    unsigned* cnt  = ws_u + POS_OFF;   // aliases pos head; dead before scatter writes

    // single memset: cnt only (1.28MB; scal ks slots zeroed inside scan_pose)
    hipMemsetAsync(ws_f + POS_OFF, 0, (size_t)10000 * CNT_STRIDE * 4u, stream);

    float fcam = (float)(320.0 / tan(39.5 * M_PI / 180.0));

    count_kernel<<<1200, 256, 0, stream>>>(obs, cnt, pack, fcam);
    scan_pose_kernel<<<1, 256, 0, stream>>>(cnt, offs, pose_obs, poses_last,
                                            scal, out + OUT_POSE);
    scatter_kernel<<<1200, 256, 0, stream>>>(obs, offs, pack, pos, feat, scal, fcam);
    gather_kernel<<<10000, 256, 0, stream>>>(pos, feat, offs, sm, out + OUT_FPMAP);
    final_kernel<<<900, 256, 0, stream>>>(maps_last, sm, scal, out + OUT_MAP);
}